// Round 6
// baseline (19243.155 us; speedup 1.0000x reference)
//
#include <hip/hip_runtime.h>
#include <stdint.h>

// Problem constants: B=4, S=2048, E=2048, H=16, HD=128
// Dtypes: inputs f32 (r3 NaN proved it); OUTPUT f32 (reference output dtype;
// r1/r2/r4/r5's bit-identical 0.21875 across 4 structurally different kernels
// proves the shared-assumption bf16-output was the bug).
// Intermediates bf16 (2% threshold = bf16-tolerant compare mode).
#define BB 4
#define SS 2048
#define EE 2048
#define HH 16
#define HD 128

typedef __attribute__((ext_vector_type(8))) short bf16x8;
typedef __attribute__((ext_vector_type(4))) float f32x4;

__device__ __forceinline__ unsigned short f2bf(float f) {
  union { float f; unsigned u; } v;
  v.f = f;
  unsigned r = (v.u + 0x7fffu + ((v.u >> 16) & 1u)) >> 16;
  return (unsigned short)r;
}
__device__ __forceinline__ float bf2f(unsigned short u) {
  union { unsigned u; float f; } v;
  v.u = ((unsigned)u) << 16;
  return v.f;
}

// async global->LDS, 16B per lane. LDS dest = wave-uniform base + lane*16.
__device__ __forceinline__ void lds16(const void* g, void* l) {
  __builtin_amdgcn_global_load_lds(
      (__attribute__((address_space(1))) void*)(uintptr_t)g,
      (__attribute__((address_space(3))) void*)(uintptr_t)l,
      16, 0, 0);
}

// ---------------- fp32 -> bf16 conversion ----------------
__global__ void cvt_f32_bf16(const float* __restrict__ src,
                             unsigned short* __restrict__ dst, int n4) {
  int i = blockIdx.x * blockDim.x + threadIdx.x;
  if (i >= n4) return;
  float4 v = ((const float4*)src)[i];
  ushort4 o;
  o.x = f2bf(v.x); o.y = f2bf(v.y); o.z = f2bf(v.z); o.w = f2bf(v.w);
  ((ushort4*)dst)[i] = o;
}

// ---------------- m97-style bt-GEMM core ----------------
// C[128x128 tile] = A[m0:,:K] @ Bm[n0:,:K]^T ; both K-major bf16.
__device__ __forceinline__ void gemm_bt_core(const unsigned short* __restrict__ A,
                                             const unsigned short* __restrict__ Bm,
                                             unsigned short* As, unsigned short* Bs,
                                             int m0, int n0, int K, f32x4 acc[4][4]) {
  const int t = threadIdx.x;
  const int w = t >> 6;
  const int lr = t & 15;
  const int lg = (t & 63) >> 4;
  const int wm = (w >> 1) * 64;
  const int wn = (w & 1) * 64;

  const unsigned short* Ag0 = A + (size_t)(m0 + (t >> 2)) * K + (t & 3) * 8;
  const unsigned short* Ag1 = Ag0 + (size_t)64 * K;
  const unsigned short* Bg0 = Bm + (size_t)(n0 + (t >> 2)) * K + (t & 3) * 8;
  const unsigned short* Bg1 = Bg0 + (size_t)64 * K;
  char* AsB = (char*)As + (w * 64) * 16;
  char* BsB = (char*)Bs + (w * 64) * 16;

#pragma unroll
  for (int i = 0; i < 4; ++i)
#pragma unroll
    for (int j = 0; j < 4; ++j)
      acc[i][j] = (f32x4){0.f, 0.f, 0.f, 0.f};

  for (int kt = 0; kt < K; kt += 32) {
    lds16(Ag0 + kt, AsB);
    lds16(Ag1 + kt, AsB + 256 * 16);
    lds16(Bg0 + kt, BsB);
    lds16(Bg1 + kt, BsB + 256 * 16);
    __syncthreads();
    bf16x8 af[4], bf[4];
#pragma unroll
    for (int i = 0; i < 4; ++i)
      af[i] = *(const bf16x8*)(As + (wm + i * 16 + lr) * 32 + lg * 8);
#pragma unroll
    for (int j = 0; j < 4; ++j)
      bf[j] = *(const bf16x8*)(Bs + (wn + j * 16 + lr) * 32 + lg * 8);
#pragma unroll
    for (int i = 0; i < 4; ++i)
#pragma unroll
      for (int j = 0; j < 4; ++j)
        acc[i][j] = __builtin_amdgcn_mfma_f32_16x16x32_bf16(af[i], bf[j], acc[i][j], 0, 0, 0);
    __syncthreads();
  }
}

// ---------------- fused QKV projection ----------------
// X[8192,2048] @ Wqkv[6144,2048]^T + bias -> Q,K,V all [b,h,s,d] bf16
__global__ __launch_bounds__(256, 2)
void gemm_qkv(const unsigned short* __restrict__ X,
              const unsigned short* __restrict__ W,
              const float* __restrict__ bq,
              const float* __restrict__ bk,
              const float* __restrict__ bv,
              unsigned short* __restrict__ Qb,
              unsigned short* __restrict__ Kb,
              unsigned short* __restrict__ Vb) {
  __shared__ __align__(16) unsigned short As[128 * 32];
  __shared__ __align__(16) unsigned short Bs[128 * 32];
  const int m0 = blockIdx.y * 128;
  const int n0 = blockIdx.x * 128;  // 0..6143
  f32x4 acc[4][4];
  gemm_bt_core(X, W, As, Bs, m0, n0, EE, acc);

  const int t = threadIdx.x;
  const int w = t >> 6;
  const int lr = t & 15;
  const int lg = (t & 63) >> 4;
  const int wm = (w >> 1) * 64;
  const int wn = (w & 1) * 64;

  const int region = n0 >> 11;  // block-uniform: 0=Q 1=K 2=V
  unsigned short* Dst = (region == 0) ? Qb : (region == 1) ? Kb : Vb;
  const float* bp = (region == 0) ? bq : (region == 1) ? bk : bv;

#pragma unroll
  for (int i = 0; i < 4; ++i) {
    const int row0 = m0 + wm + i * 16 + lg * 4;  // b*S + s, s%4==0
    const int b = row0 >> 11;
    const int s = row0 & 2047;
#pragma unroll
    for (int j = 0; j < 4; ++j) {
      const int c = (n0 + wn + j * 16 + lr) & 2047;  // col within region
      const float bias = bp[c];
      const int h = c >> 7, hd = c & 127;
      const size_t base = ((size_t)(b * HH + h) * SS + s) * HD + hd;
#pragma unroll
      for (int re = 0; re < 4; ++re)
        Dst[base + (size_t)re * HD] = f2bf(acc[i][j][re] + bias);
    }
  }
}

// ---------------- output projection (f32 output!) ----------------
__global__ __launch_bounds__(256, 2)
void gemm_out(const unsigned short* __restrict__ A,
              const unsigned short* __restrict__ W,
              const float* __restrict__ bo,
              float* __restrict__ Out) {
  __shared__ __align__(16) unsigned short As[128 * 32];
  __shared__ __align__(16) unsigned short Bs[128 * 32];
  const int m0 = blockIdx.y * 128;
  const int n0 = blockIdx.x * 128;
  f32x4 acc[4][4];
  gemm_bt_core(A, W, As, Bs, m0, n0, EE, acc);

  const int t = threadIdx.x;
  const int w = t >> 6;
  const int lr = t & 15;
  const int lg = (t & 63) >> 4;
  const int wm = (w >> 1) * 64;
  const int wn = (w & 1) * 64;

#pragma unroll
  for (int i = 0; i < 4; ++i) {
    const int row0 = m0 + wm + i * 16 + lg * 4;
#pragma unroll
    for (int j = 0; j < 4; ++j) {
      const int col = n0 + wn + j * 16 + lr;
      const float bias = bo[col];
#pragma unroll
      for (int re = 0; re < 4; ++re)
        Out[(size_t)(row0 + re) * EE + col] = acc[i][j][re] + bias;
    }
  }
}

// ---------------- NAIVE attention (f32, no MFMA) ----------------
// One block per (q, b*H+h). 256 threads. Full-S softmax (mask is a no-op).
__global__ __launch_bounds__(256)
void attn_naive(const unsigned short* __restrict__ Qb,
                const unsigned short* __restrict__ Kb,
                const unsigned short* __restrict__ Vb,
                unsigned short* __restrict__ Attn) {
  __shared__ float qrow[HD];
  __shared__ float sc[SS];
  __shared__ float red[8];
  const int t = threadIdx.x;
  const int q = blockIdx.x;
  const int bh = blockIdx.y;
  const unsigned short* Qr = Qb + ((size_t)bh * SS + q) * HD;
  const unsigned short* Kh = Kb + (size_t)bh * SS * HD;
  const unsigned short* Vh = Vb + (size_t)bh * SS * HD;

  if (t < HD) qrow[t] = bf2f(Qr[t]);
  __syncthreads();

  // scores: thread t owns keys t, t+256, ... (8 each)
  float sloc[8];
#pragma unroll
  for (int i = 0; i < 8; ++i) {
    const int k = t + i * 256;
    const unsigned short* Kr = Kh + (size_t)k * HD;
    float s = 0.f;
    for (int d = 0; d < HD; d += 4) {
      ushort4 k4 = *(const ushort4*)(Kr + d);
      s += qrow[d] * bf2f(k4.x) + qrow[d + 1] * bf2f(k4.y) +
           qrow[d + 2] * bf2f(k4.z) + qrow[d + 3] * bf2f(k4.w);
    }
    sloc[i] = s * 0.08838834764831845f;  // 1/sqrt(HD)
  }

  // block max
  float m = sloc[0];
#pragma unroll
  for (int i = 1; i < 8; ++i) m = fmaxf(m, sloc[i]);
  for (int off = 32; off; off >>= 1) m = fmaxf(m, __shfl_xor(m, off, 64));
  if ((t & 63) == 0) red[t >> 6] = m;
  __syncthreads();
  m = fmaxf(fmaxf(red[0], red[1]), fmaxf(red[2], red[3]));

  // exp + sum; p -> sc
  float l = 0.f;
#pragma unroll
  for (int i = 0; i < 8; ++i) {
    const float p = expf(sloc[i] - m);
    sc[t + i * 256] = p;
    l += p;
  }
  for (int off = 32; off; off >>= 1) l += __shfl_xor(l, off, 64);
  if ((t & 63) == 0) red[4 + (t >> 6)] = l;
  __syncthreads();  // sc + red[4..7] visible
  l = red[4] + red[5] + red[6] + red[7];

  // PV: threads 0..127 own output dim d (coalesced V reads)
  if (t < HD) {
    float o = 0.f;
    for (int k = 0; k < SS; ++k) o += sc[k] * bf2f(Vh[(size_t)k * HD + t]);
    const int b = bh >> 4, h = bh & 15;
    Attn[((size_t)(b * SS + q)) * EE + h * HD + t] = f2bf(o / l);
  }
}

// ---------------- launcher ----------------
extern "C" void kernel_launch(void* const* d_in, const int* in_sizes, int n_in,
                              void* d_out, int out_size, void* d_ws, size_t ws_size,
                              hipStream_t stream) {
  const float* QKV = (const float*)d_in[0];
  const float* Wq  = (const float*)d_in[1];
  const float* bq  = (const float*)d_in[2];
  const float* Wk  = (const float*)d_in[3];
  const float* bk  = (const float*)d_in[4];
  const float* Wv  = (const float*)d_in[5];
  const float* bv  = (const float*)d_in[6];
  const float* Wo  = (const float*)d_in[7];
  const float* bo  = (const float*)d_in[8];
  // d_in[9] = is_causal: masking is a no-op in the reference

  // X-bf16 lives in d_out's first 32 MiB (d_out is 64 MiB f32; X is dead
  // before gemm_out writes the f32 result over the whole buffer).
  unsigned short* Xb = (unsigned short*)d_out;

  char* ws = (char*)d_ws;  // ws use: 152 MiB
  unsigned short* Wqkvb = (unsigned short*)(ws);                 // [  0, 24M)
  unsigned short* Qb    = (unsigned short*)(ws + ( 24u << 20));  // [ 24, 56M)
  unsigned short* Kb    = (unsigned short*)(ws + ( 56u << 20));  // [ 56, 88M)
  unsigned short* Vb    = (unsigned short*)(ws + ( 88u << 20));  // [ 88,120M)
  unsigned short* At    = (unsigned short*)(ws + (120u << 20));  // [120,152M)
  unsigned short* Wob   = Wqkvb;  // reuses dead Wqkv region

  cvt_f32_bf16<<<dim3(16384), dim3(256), 0, stream>>>(QKV, Xb, 4194304);
  cvt_f32_bf16<<<dim3(4096), dim3(256), 0, stream>>>(Wq, Wqkvb, 1048576);
  cvt_f32_bf16<<<dim3(4096), dim3(256), 0, stream>>>(Wk, Wqkvb + 4194304, 1048576);
  cvt_f32_bf16<<<dim3(4096), dim3(256), 0, stream>>>(Wv, Wqkvb + 8388608, 1048576);

  gemm_qkv<<<dim3(48, 64), dim3(256), 0, stream>>>(Xb, Wqkvb, bq, bk, bv, Qb, Kb, Vb);
  attn_naive<<<dim3(SS, BB * HH), dim3(256), 0, stream>>>(Qb, Kb, Vb, At);

  cvt_f32_bf16<<<dim3(4096), dim3(256), 0, stream>>>(Wo, Wob, 1048576);
  gemm_out<<<dim3(16, 64), dim3(256), 0, stream>>>(At, Wob, bo, (float*)d_out);
}